// Round 3
// baseline (1257.575 us; speedup 1.0000x reference)
//
#include <hip/hip_runtime.h>
#include <hip/hip_bf16.h>
#include <stdint.h>

// Problem constants (from reference)
#define KVOL   27
#define MPAIRS 150000
#define NROWS  200000            // N_IN == N_OUT
#define CDIM   64
#define NPASS  3
#define KPP    9                 // kernel offsets per pass
#define TOTALC (KVOL*MPAIRS)     // 4,050,000 contributions
#define NBINS  (NPASS*NROWS)     // 600,000 (per-pass row bins)

typedef __attribute__((ext_vector_type(8))) short bf16x8;   // 8 bf16 = 4 VGPRs
typedef __attribute__((ext_vector_type(4))) float f32x4;

__device__ __forceinline__ short f2bf(float f) {
  union { float f; uint32_t u; } v; v.f = f;
  uint32_t u = v.u;
  u += 0x7FFF + ((u >> 16) & 1);   // round-to-nearest-even
  return (short)(u >> 16);
}
__device__ __forceinline__ float bf2f(uint16_t u) {
  union { uint32_t u; float f; } v; v.u = ((uint32_t)u) << 16; return v.f;
}

// ---- prologue: in_feats f32 -> bf16 ----
__global__ void cvt_feats(const float* __restrict__ in, short* __restrict__ out, int n8) {
  int i = blockIdx.x * blockDim.x + threadIdx.x;
  int stride = gridDim.x * blockDim.x;
  for (; i < n8; i += stride) {
    const float* p = in + (size_t)i * 8;
    f32x4 f0 = *(const f32x4*)(p);
    f32x4 f1 = *(const f32x4*)(p + 4);
    bf16x8 o;
    o[0] = f2bf(f0[0]); o[1] = f2bf(f0[1]); o[2] = f2bf(f0[2]); o[3] = f2bf(f0[3]);
    o[4] = f2bf(f1[0]); o[5] = f2bf(f1[1]); o[6] = f2bf(f1[2]); o[7] = f2bf(f1[3]);
    *(bf16x8*)(out + (size_t)i * 8) = o;
  }
}

// ---- prologue: W [27][64][64] f32 -> W^T bf16 as wt[k][j][i] ----
__global__ void cvt_w(const float* __restrict__ w, short* __restrict__ wt) {
  int k = blockIdx.x;
  const float* wk = w + (size_t)k * CDIM * CDIM;
  short* wtk = wt + (size_t)k * CDIM * CDIM;
  for (int t = threadIdx.x; t < CDIM * CDIM; t += blockDim.x) {
    int j = t >> 6, i = t & 63;
    wtk[j * CDIM + i] = f2bf(wk[i * CDIM + j]);
  }
}

// ---- CSR build: count contributions per (pass, out_row) ----
__global__ void count_contrib(const int* __restrict__ out_map, unsigned int* __restrict__ counts) {
  int e = blockIdx.x * blockDim.x + threadIdx.x;
  if (e >= TOTALC) return;
  int k = e / MPAIRS;
  int p = k / KPP;
  int o = out_map[e];
  atomicAdd(&counts[p * NROWS + o], 1u);
}

// ---- 3-kernel exclusive scan over NBINS ----
__global__ void scan_local(const unsigned int* __restrict__ counts,
                           unsigned int* __restrict__ offsets,
                           unsigned int* __restrict__ bsum) {
  __shared__ unsigned int sh[1024];
  int t = threadIdx.x;
  int idx = blockIdx.x * 1024 + t;
  unsigned int v = (idx < NBINS) ? counts[idx] : 0u;
  sh[t] = v; __syncthreads();
  for (int o = 1; o < 1024; o <<= 1) {
    unsigned int u = (t >= o) ? sh[t - o] : 0u;
    __syncthreads();
    sh[t] += u;
    __syncthreads();
  }
  if (idx < NBINS) offsets[idx] = sh[t] - v;      // exclusive within block
  if (t == 1023) bsum[blockIdx.x] = sh[1023];     // block total
}

__global__ void scan_bsum(unsigned int* __restrict__ bsum, int nb) {
  __shared__ unsigned int sh[1024];
  int t = threadIdx.x;
  unsigned int v = (t < nb) ? bsum[t] : 0u;
  sh[t] = v; __syncthreads();
  for (int o = 1; o < 1024; o <<= 1) {
    unsigned int u = (t >= o) ? sh[t - o] : 0u;
    __syncthreads();
    sh[t] += u;
    __syncthreads();
  }
  if (t < nb) bsum[t] = sh[t] - v;                // exclusive block bases
}

__global__ void scan_apply(unsigned int* __restrict__ offsets,
                           unsigned int* __restrict__ cursors,
                           const unsigned int* __restrict__ bsum) {
  int t = threadIdx.x;
  int idx = blockIdx.x * 1024 + t;
  if (idx < NBINS) {
    unsigned int o = offsets[idx] + bsum[blockIdx.x];
    offsets[idx] = o;
    cursors[idx] = o;
  }
  if (idx == 0) offsets[NBINS] = (unsigned int)TOTALC;
}

// ---- CSR fill: scatter contribution ids (local row within pass-contrib buffer) ----
__global__ void fill_ids(const int* __restrict__ out_map,
                         unsigned int* __restrict__ cursors,
                         unsigned int* __restrict__ ids) {
  int e = blockIdx.x * blockDim.x + threadIdx.x;
  if (e >= TOTALC) return;
  int k = e / MPAIRS;
  int m = e - k * MPAIRS;
  int p = k / KPP;
  int kk = k - p * KPP;
  int o = out_map[e];
  unsigned int pos = atomicAdd(&cursors[p * NROWS + o], 1u);
  ids[pos] = (unsigned int)(kk * MPAIRS + m);
}

// ---- GEMM pass: per-pair contribution rows, NO atomics.
// Swapped MFMA (D' = W^T x X^T): lane (r,h) owns pair base+r, channels t*16+h*4+{0..3}.
__global__ __launch_bounds__(256, 4)
void gemm_pass(const short* __restrict__ a_bf16,   // [NROWS][64] bf16
               const short* __restrict__ wt_bf16,  // [27][64 out][64 in] bf16
               const int*   __restrict__ in_map,   // [27][M]
               short*       __restrict__ contrib,  // [KPP*M][64] bf16
               int pass)
{
  const int kk   = blockIdx.y;
  const int k    = pass * KPP + kk;
  const int lane = threadIdx.x & 63;
  const int wave = threadIdx.x >> 6;
  const int r    = lane & 15;
  const int h    = lane >> 4;

  bf16x8 b[4][2];
  const short* wtk = wt_bf16 + (size_t)k * CDIM * CDIM;
#pragma unroll
  for (int t = 0; t < 4; ++t)
#pragma unroll
    for (int c = 0; c < 2; ++c)
      b[t][c] = *(const bf16x8*)(wtk + (t * 16 + r) * CDIM + c * 32 + h * 8);

  const int* imk = in_map + (size_t)k * MPAIRS;
  const int ntiles = MPAIRS / 16;
  const int wstride = gridDim.x * 4;

  for (int tile = blockIdx.x * 4 + wave; tile < ntiles; tile += wstride) {
    const int base = tile * 16;
    const int in_row = imk[base + r];
    const short* arow = a_bf16 + (size_t)in_row * CDIM;
    bf16x8 a0 = *(const bf16x8*)(arow + h * 8);
    bf16x8 a1 = *(const bf16x8*)(arow + 32 + h * 8);

    f32x4 acc[4];
#pragma unroll
    for (int t = 0; t < 4; ++t) {
      acc[t] = (f32x4){0.f, 0.f, 0.f, 0.f};
      acc[t] = __builtin_amdgcn_mfma_f32_16x16x32_bf16(b[t][0], a0, acc[t], 0, 0, 0);
      acc[t] = __builtin_amdgcn_mfma_f32_16x16x32_bf16(b[t][1], a1, acc[t], 0, 0, 0);
    }

    short* crow = contrib + ((size_t)(kk * MPAIRS + base + r)) * CDIM;
#pragma unroll
    for (int t = 0; t < 4; ++t) {
      short4 s4;
      s4.x = f2bf(acc[t][0]); s4.y = f2bf(acc[t][1]);
      s4.z = f2bf(acc[t][2]); s4.w = f2bf(acc[t][3]);
      *(short4*)(crow + t * 16 + h * 4) = s4;
    }
  }
}

// ---- reduce pass: one wave per output row; gather contrib rows via CSR; no atomics ----
__global__ __launch_bounds__(256, 8)
void reduce_pass(const short* __restrict__ contrib,
                 const unsigned int* __restrict__ ids,
                 const unsigned int* __restrict__ offsets,
                 float* __restrict__ out, int pass)
{
  int gw = (blockIdx.x * blockDim.x + threadIdx.x) >> 6;   // global wave = out row
  if (gw >= NROWS) return;
  int lane = threadIdx.x & 63;
  const unsigned int* offp = offsets + (size_t)pass * NROWS;
  unsigned int s = offp[gw], e = offp[gw + 1];

  float acc = 0.f;
  if (pass > 0) {
    if (s == e) return;                       // nothing to add this pass
    acc = out[(size_t)gw * CDIM + lane];
  }
  const uint16_t* cb = (const uint16_t*)contrib;
  for (unsigned int j = s; j < e; ++j) {
    unsigned int c = ids[j];
    acc += bf2f(cb[(size_t)c * CDIM + lane]);
  }
  out[(size_t)gw * CDIM + lane] = acc;
}

extern "C" void kernel_launch(void* const* d_in, const int* in_sizes, int n_in,
                              void* d_out, int out_size, void* d_ws, size_t ws_size,
                              hipStream_t stream) {
  const float* in_feats = (const float*)d_in[0];   // [200000][64]
  const float* kernel   = (const float*)d_in[1];   // [27][64][64]
  const int*   in_map   = (const int*)d_in[2];     // [27][150000]
  const int*   out_map  = (const int*)d_in[3];     // [27][150000]
  float* out = (float*)d_out;                      // [200000][64]

  uint8_t* ws = (uint8_t*)d_ws;
  size_t off = 0;
  auto alloc = [&](size_t bytes) -> void* {
    void* p = ws + off;
    off += (bytes + 255) & ~(size_t)255;
    return p;
  };
  short* in_bf16        = (short*)alloc((size_t)NROWS * CDIM * 2);         // 25.6 MB
  short* wt_bf16        = (short*)alloc((size_t)KVOL * CDIM * CDIM * 2);   // 221 KB
  unsigned int* counts  = (unsigned int*)alloc((size_t)NBINS * 4);         // 2.4 MB (reused as cursors)
  unsigned int* offsets = (unsigned int*)alloc((size_t)(NBINS + 1) * 4);   // 2.4 MB
  unsigned int* bsum    = (unsigned int*)alloc(4096);
  unsigned int* ids     = (unsigned int*)alloc((size_t)TOTALC * 4);        // 16.2 MB
  short* contrib        = (short*)alloc((size_t)KPP * MPAIRS * CDIM * 2);  // 172.8 MB

  hipMemsetAsync(counts, 0, (size_t)NBINS * 4, stream);

  cvt_feats<<<2048, 256, 0, stream>>>(in_feats, in_bf16, NROWS * CDIM / 8);
  cvt_w<<<KVOL, 256, 0, stream>>>(kernel, wt_bf16);

  const int cb = (TOTALC + 255) / 256;
  count_contrib<<<cb, 256, 0, stream>>>(out_map, counts);

  const int sb = (NBINS + 1023) / 1024;   // 587
  scan_local<<<sb, 1024, 0, stream>>>(counts, offsets, bsum);
  scan_bsum<<<1, 1024, 0, stream>>>(bsum, sb);
  scan_apply<<<sb, 1024, 0, stream>>>(offsets, counts, bsum);

  fill_ids<<<cb, 256, 0, stream>>>(out_map, counts, ids);

  for (int p = 0; p < NPASS; ++p) {
    dim3 g(192, KPP);
    gemm_pass<<<g, 256, 0, stream>>>(in_bf16, wt_bf16, in_map, contrib, p);
    reduce_pass<<<NROWS / 4, 256, 0, stream>>>(contrib, ids, offsets, out, p);
  }
}

// Round 4
// 848.853 us; speedup vs baseline: 1.4815x; 1.4815x over previous
//
#include <hip/hip_runtime.h>
#include <hip/hip_bf16.h>
#include <stdint.h>

// Problem constants (from reference)
#define KVOL   27
#define MPAIRS 150000
#define NROWS  200000            // N_IN == N_OUT
#define CDIM   64
#define NPASS  3
#define KPP    9                 // kernel offsets per pass
#define PASSC  (KPP*MPAIRS)      // 1,350,000 contributions per pass (exact)
#define TOTALC (KVOL*MPAIRS)     // 4,050,000
#define NBINS  (NPASS*NROWS)     // 600,000 (per-pass row bins)

typedef __attribute__((ext_vector_type(8))) short bf16x8;   // 8 bf16 = 4 VGPRs
typedef __attribute__((ext_vector_type(4))) float f32x4;

__device__ __forceinline__ short f2bf(float f) {
  union { float f; uint32_t u; } v; v.f = f;
  uint32_t u = v.u;
  u += 0x7FFF + ((u >> 16) & 1);   // round-to-nearest-even
  return (short)(u >> 16);
}
__device__ __forceinline__ float bf2f(uint16_t u) {
  union { uint32_t u; float f; } v; v.u = ((uint32_t)u) << 16; return v.f;
}

// ---- prologue: in_feats f32 -> bf16 ----
__global__ void cvt_feats(const float* __restrict__ in, short* __restrict__ out, int n8) {
  int i = blockIdx.x * blockDim.x + threadIdx.x;
  int stride = gridDim.x * blockDim.x;
  for (; i < n8; i += stride) {
    const float* p = in + (size_t)i * 8;
    f32x4 f0 = *(const f32x4*)(p);
    f32x4 f1 = *(const f32x4*)(p + 4);
    bf16x8 o;
    o[0] = f2bf(f0[0]); o[1] = f2bf(f0[1]); o[2] = f2bf(f0[2]); o[3] = f2bf(f0[3]);
    o[4] = f2bf(f1[0]); o[5] = f2bf(f1[1]); o[6] = f2bf(f1[2]); o[7] = f2bf(f1[3]);
    *(bf16x8*)(out + (size_t)i * 8) = o;
  }
}

// ---- prologue: W [27][64][64] f32 -> W^T bf16 as wt[k][j][i] ----
__global__ void cvt_w(const float* __restrict__ w, short* __restrict__ wt) {
  int k = blockIdx.x;
  const float* wk = w + (size_t)k * CDIM * CDIM;
  short* wtk = wt + (size_t)k * CDIM * CDIM;
  for (int t = threadIdx.x; t < CDIM * CDIM; t += blockDim.x) {
    int j = t >> 6, i = t & 63;
    wtk[j * CDIM + i] = f2bf(wk[i * CDIM + j]);
  }
}

// ---- CSR build: count contributions per (pass, out_row) ----
__global__ void count_contrib(const int* __restrict__ out_map, unsigned int* __restrict__ counts) {
  int e = blockIdx.x * blockDim.x + threadIdx.x;
  if (e >= TOTALC) return;
  int k = e / MPAIRS;
  int p = k / KPP;
  int o = out_map[e];
  atomicAdd(&counts[p * NROWS + o], 1u);
}

// ---- 3-kernel exclusive scan over NBINS ----
__global__ void scan_local(const unsigned int* __restrict__ counts,
                           unsigned int* __restrict__ offsets,
                           unsigned int* __restrict__ bsum) {
  __shared__ unsigned int sh[1024];
  int t = threadIdx.x;
  int idx = blockIdx.x * 1024 + t;
  unsigned int v = (idx < NBINS) ? counts[idx] : 0u;
  sh[t] = v; __syncthreads();
  for (int o = 1; o < 1024; o <<= 1) {
    unsigned int u = (t >= o) ? sh[t - o] : 0u;
    __syncthreads();
    sh[t] += u;
    __syncthreads();
  }
  if (idx < NBINS) offsets[idx] = sh[t] - v;      // exclusive within block
  if (t == 1023) bsum[blockIdx.x] = sh[1023];     // block total
}

__global__ void scan_bsum(unsigned int* __restrict__ bsum, int nb) {
  __shared__ unsigned int sh[1024];
  int t = threadIdx.x;
  unsigned int v = (t < nb) ? bsum[t] : 0u;
  sh[t] = v; __syncthreads();
  for (int o = 1; o < 1024; o <<= 1) {
    unsigned int u = (t >= o) ? sh[t - o] : 0u;
    __syncthreads();
    sh[t] += u;
    __syncthreads();
  }
  if (t < nb) bsum[t] = sh[t] - v;                // exclusive block bases
}

__global__ void scan_apply(unsigned int* __restrict__ offsets,
                           unsigned int* __restrict__ cursors,
                           const unsigned int* __restrict__ bsum) {
  int t = threadIdx.x;
  int idx = blockIdx.x * 1024 + t;
  if (idx < NBINS) {
    unsigned int o = offsets[idx] + bsum[blockIdx.x];
    offsets[idx] = o;
    cursors[idx] = o;
  }
  if (idx == 0) offsets[NBINS] = (unsigned int)TOTALC;
}

// ---- GEMM pass: contribution rows written DIRECTLY at their CSR-sorted
// position (pos from per-row atomic cursor). No ids array, no fill kernel.
// Swapped MFMA (D' = W^T x X^T): lane (r,h) owns pair base+r, channels t*16+h*4+{0..3}.
__global__ __launch_bounds__(256, 4)
void gemm_pass(const short* __restrict__ a_bf16,   // [NROWS][64] bf16
               const short* __restrict__ wt_bf16,  // [27][64 out][64 in] bf16
               const int*   __restrict__ in_map,   // [27][M]
               const int*   __restrict__ out_map,  // [27][M]
               unsigned int* __restrict__ cursors, // [NPASS][NROWS], global positions
               short*       __restrict__ contrib,  // [PASSC][64] bf16 (pass-local)
               int pass)
{
  const int kk   = blockIdx.y;
  const int k    = pass * KPP + kk;
  const int lane = threadIdx.x & 63;
  const int wave = threadIdx.x >> 6;
  const int r    = lane & 15;
  const int h    = lane >> 4;

  bf16x8 b[4][2];
  const short* wtk = wt_bf16 + (size_t)k * CDIM * CDIM;
#pragma unroll
  for (int t = 0; t < 4; ++t)
#pragma unroll
    for (int c = 0; c < 2; ++c)
      b[t][c] = *(const bf16x8*)(wtk + (t * 16 + r) * CDIM + c * 32 + h * 8);

  const int* imk = in_map  + (size_t)k * MPAIRS;
  const int* omk = out_map + (size_t)k * MPAIRS;
  unsigned int* curp = cursors + (size_t)pass * NROWS;
  const unsigned int pbase = (unsigned int)pass * (unsigned int)PASSC;
  const int ntiles = MPAIRS / 16;
  const int wstride = gridDim.x * 4;

  for (int tile = blockIdx.x * 4 + wave; tile < ntiles; tile += wstride) {
    const int base = tile * 16;
    const int in_row = imk[base + r];
    const short* arow = a_bf16 + (size_t)in_row * CDIM;
    bf16x8 a0 = *(const bf16x8*)(arow + h * 8);
    bf16x8 a1 = *(const bf16x8*)(arow + 32 + h * 8);

    // claim the CSR slot for this pair (one atomic per pair, lanes 0..15)
    unsigned int pos = 0;
    const int orow = omk[base + r];
    if (lane < 16) pos = atomicAdd(&curp[orow], 1u);

    f32x4 acc[4];
#pragma unroll
    for (int t = 0; t < 4; ++t) {
      acc[t] = (f32x4){0.f, 0.f, 0.f, 0.f};
      acc[t] = __builtin_amdgcn_mfma_f32_16x16x32_bf16(b[t][0], a0, acc[t], 0, 0, 0);
      acc[t] = __builtin_amdgcn_mfma_f32_16x16x32_bf16(b[t][1], a1, acc[t], 0, 0, 0);
    }

    pos = __shfl(pos, r);                    // broadcast pair r's slot to its 4 lanes
    short* crow = contrib + (size_t)(pos - pbase) * CDIM;
#pragma unroll
    for (int t = 0; t < 4; ++t) {
      short4 s4;
      s4.x = f2bf(acc[t][0]); s4.y = f2bf(acc[t][1]);
      s4.z = f2bf(acc[t][2]); s4.w = f2bf(acc[t][3]);
      *(short4*)(crow + t * 16 + h * 4) = s4;
    }
  }
}

// ---- reduce pass: one wave per output row; CONTIGUOUS segment of contrib ----
__global__ __launch_bounds__(256, 8)
void reduce_pass(const short* __restrict__ contrib,
                 const unsigned int* __restrict__ offsets,
                 float* __restrict__ out, int pass)
{
  int gw = (blockIdx.x * blockDim.x + threadIdx.x) >> 6;   // global wave = out row
  if (gw >= NROWS) return;
  int lane = threadIdx.x & 63;
  const unsigned int* offp = offsets + (size_t)pass * NROWS;
  const unsigned int pbase = (unsigned int)pass * (unsigned int)PASSC;
  unsigned int s = offp[gw], e = offp[gw + 1];

  float acc = 0.f;
  if (pass > 0) {
    if (s == e) return;                       // nothing to add this pass
    acc = out[(size_t)gw * CDIM + lane];
  }
  const uint16_t* cb = (const uint16_t*)contrib;
  for (unsigned int j = s; j < e; ++j) {
    acc += bf2f(cb[(size_t)(j - pbase) * CDIM + lane]);
  }
  out[(size_t)gw * CDIM + lane] = acc;
}

extern "C" void kernel_launch(void* const* d_in, const int* in_sizes, int n_in,
                              void* d_out, int out_size, void* d_ws, size_t ws_size,
                              hipStream_t stream) {
  const float* in_feats = (const float*)d_in[0];   // [200000][64]
  const float* kernel   = (const float*)d_in[1];   // [27][64][64]
  const int*   in_map   = (const int*)d_in[2];     // [27][150000]
  const int*   out_map  = (const int*)d_in[3];     // [27][150000]
  float* out = (float*)d_out;                      // [200000][64]

  uint8_t* ws = (uint8_t*)d_ws;
  size_t off = 0;
  auto alloc = [&](size_t bytes) -> void* {
    void* p = ws + off;
    off += (bytes + 255) & ~(size_t)255;
    return p;
  };
  short* in_bf16        = (short*)alloc((size_t)NROWS * CDIM * 2);         // 25.6 MB
  short* wt_bf16        = (short*)alloc((size_t)KVOL * CDIM * CDIM * 2);   // 221 KB
  unsigned int* counts  = (unsigned int*)alloc((size_t)NBINS * 4);         // 2.4 MB (becomes cursors)
  unsigned int* offsets = (unsigned int*)alloc((size_t)(NBINS + 1) * 4);   // 2.4 MB
  unsigned int* bsum    = (unsigned int*)alloc(4096);
  short* contrib        = (short*)alloc((size_t)PASSC * CDIM * 2);         // 172.8 MB

  hipMemsetAsync(counts, 0, (size_t)NBINS * 4, stream);

  cvt_feats<<<2048, 256, 0, stream>>>(in_feats, in_bf16, NROWS * CDIM / 8);
  cvt_w<<<KVOL, 256, 0, stream>>>(kernel, wt_bf16);

  const int cb = (TOTALC + 255) / 256;
  count_contrib<<<cb, 256, 0, stream>>>(out_map, counts);

  const int sb = (NBINS + 1023) / 1024;   // 587
  scan_local<<<sb, 1024, 0, stream>>>(counts, offsets, bsum);
  scan_bsum<<<1, 1024, 0, stream>>>(bsum, sb);
  scan_apply<<<sb, 1024, 0, stream>>>(offsets, counts, bsum);

  for (int p = 0; p < NPASS; ++p) {
    dim3 g(192, KPP);
    gemm_pass<<<g, 256, 0, stream>>>(in_bf16, wt_bf16, in_map, out_map, counts, contrib, p);
    reduce_pass<<<NROWS / 4, 256, 0, stream>>>(contrib, offsets, out, p);
  }
}

// Round 5
// 816.974 us; speedup vs baseline: 1.5393x; 1.0390x over previous
//
#include <hip/hip_runtime.h>
#include <hip/hip_bf16.h>
#include <stdint.h>

// Problem constants (from reference)
#define KVOL   27
#define MPAIRS 150000
#define NROWS  200000            // N_IN == N_OUT
#define CDIM   64
#define NPASS  3
#define KPP    9                 // kernel offsets per pass
#define PASSC  (KPP*MPAIRS)      // 1,350,000 contributions per pass (exact)
#define TOTALC (KVOL*MPAIRS)     // 4,050,000
#define NBINS  (NPASS*NROWS)     // 600,000 (per-pass row bins)
#define NCOPY  8                 // privatized count copies (~per-XCD)

typedef __attribute__((ext_vector_type(8))) short bf16x8;   // 8 bf16 = 4 VGPRs
typedef __attribute__((ext_vector_type(4))) float f32x4;

__device__ __forceinline__ short f2bf(float f) {
  union { float f; uint32_t u; } v; v.f = f;
  uint32_t u = v.u;
  u += 0x7FFF + ((u >> 16) & 1);   // round-to-nearest-even
  return (short)(u >> 16);
}
__device__ __forceinline__ float bf2f(uint16_t u) {
  union { uint32_t u; float f; } v; v.u = ((uint32_t)u) << 16; return v.f;
}

// ---- prologue: in_feats f32 -> bf16 ----
__global__ void cvt_feats(const float* __restrict__ in, short* __restrict__ out, int n8) {
  int i = blockIdx.x * blockDim.x + threadIdx.x;
  int stride = gridDim.x * blockDim.x;
  for (; i < n8; i += stride) {
    const float* p = in + (size_t)i * 8;
    f32x4 f0 = *(const f32x4*)(p);
    f32x4 f1 = *(const f32x4*)(p + 4);
    bf16x8 o;
    o[0] = f2bf(f0[0]); o[1] = f2bf(f0[1]); o[2] = f2bf(f0[2]); o[3] = f2bf(f0[3]);
    o[4] = f2bf(f1[0]); o[5] = f2bf(f1[1]); o[6] = f2bf(f1[2]); o[7] = f2bf(f1[3]);
    *(bf16x8*)(out + (size_t)i * 8) = o;
  }
}

// ---- prologue: W [27][64][64] f32 -> W^T bf16 as wt[k][j][i] ----
__global__ void cvt_w(const float* __restrict__ w, short* __restrict__ wt) {
  int k = blockIdx.x;
  const float* wk = w + (size_t)k * CDIM * CDIM;
  short* wtk = wt + (size_t)k * CDIM * CDIM;
  for (int t = threadIdx.x; t < CDIM * CDIM; t += blockDim.x) {
    int j = t >> 6, i = t & 63;
    wtk[j * CDIM + i] = f2bf(wk[i * CDIM + j]);
  }
}

// ---- fused count + rank claim, privatized 8 ways.
// cnt8 layout: [NCOPY][NBINS] (plane-major). rankpack[e] = (rank<<3)|copy.
__global__ void count_rank(const int* __restrict__ out_map,
                           unsigned int* __restrict__ cnt8,
                           unsigned short* __restrict__ rankpack) {
  int e = blockIdx.x * blockDim.x + threadIdx.x;
  if (e >= TOTALC) return;
  int k = e / MPAIRS;
  int p = k / KPP;
  int o = out_map[e];
  int c = blockIdx.x & (NCOPY - 1);
  unsigned int r8 = atomicAdd(&cnt8[(size_t)c * NBINS + p * NROWS + o], 1u);
  rankpack[e] = (unsigned short)((r8 << 3) | (unsigned)c);
}

// ---- 3-kernel exclusive scan over NBINS (summing the 8 privatized planes) ----
__global__ void scan_local(const unsigned int* __restrict__ cnt8,
                           unsigned int* __restrict__ offsets,
                           unsigned int* __restrict__ bsum) {
  __shared__ unsigned int sh[1024];
  int t = threadIdx.x;
  int idx = blockIdx.x * 1024 + t;
  unsigned int v = 0u;
  if (idx < NBINS) {
#pragma unroll
    for (int c = 0; c < NCOPY; ++c) v += cnt8[(size_t)c * NBINS + idx];
  }
  sh[t] = v; __syncthreads();
  for (int o = 1; o < 1024; o <<= 1) {
    unsigned int u = (t >= o) ? sh[t - o] : 0u;
    __syncthreads();
    sh[t] += u;
    __syncthreads();
  }
  if (idx < NBINS) offsets[idx] = sh[t] - v;      // exclusive within block
  if (t == 1023) bsum[blockIdx.x] = sh[1023];     // block total
}

__global__ void scan_bsum(unsigned int* __restrict__ bsum, int nb) {
  __shared__ unsigned int sh[1024];
  int t = threadIdx.x;
  unsigned int v = (t < nb) ? bsum[t] : 0u;
  sh[t] = v; __syncthreads();
  for (int o = 1; o < 1024; o <<= 1) {
    unsigned int u = (t >= o) ? sh[t - o] : 0u;
    __syncthreads();
    sh[t] += u;
    __syncthreads();
  }
  if (t < nb) bsum[t] = sh[t] - v;                // exclusive block bases
}

__global__ void scan_apply(unsigned int* __restrict__ offsets,
                           const unsigned int* __restrict__ bsum) {
  int t = threadIdx.x;
  int idx = blockIdx.x * 1024 + t;
  if (idx < NBINS) offsets[idx] += bsum[blockIdx.x];
  if (idx == 0) offsets[NBINS] = (unsigned int)TOTALC;
}

// ---- per-(bin,copy) global base offsets: base8[bin][c] ----
__global__ void base_fill(const unsigned int* __restrict__ cnt8,
                          const unsigned int* __restrict__ offsets,
                          unsigned int* __restrict__ base8) {
  int idx = blockIdx.x * 1024 + threadIdx.x;
  if (idx >= NBINS) return;
  unsigned int run = offsets[idx];
#pragma unroll
  for (int c = 0; c < NCOPY; ++c) {
    base8[(size_t)idx * NCOPY + c] = run;
    run += cnt8[(size_t)c * NBINS + idx];
  }
}

// ---- GEMM pass: contribution rows written at their CSR slot, slot derived
// from rankpack + base8 (NO atomics). Swapped MFMA (D' = W^T x X^T):
// lane (r,h) owns pair base+r, channels t*16+h*4+{0..3}.
__global__ __launch_bounds__(256, 4)
void gemm_pass(const short* __restrict__ a_bf16,   // [NROWS][64] bf16
               const short* __restrict__ wt_bf16,  // [27][64 out][64 in] bf16
               const int*   __restrict__ in_map,   // [27][M]
               const int*   __restrict__ out_map,  // [27][M]
               const unsigned short* __restrict__ rankpack, // [27][M]
               const unsigned int*   __restrict__ base8,    // [NBINS][8]
               short*       __restrict__ contrib,  // [PASSC][64] bf16 (pass-local)
               int pass)
{
  const int kk   = blockIdx.y;
  const int k    = pass * KPP + kk;
  const int lane = threadIdx.x & 63;
  const int wave = threadIdx.x >> 6;
  const int r    = lane & 15;
  const int h    = lane >> 4;

  bf16x8 b[4][2];
  const short* wtk = wt_bf16 + (size_t)k * CDIM * CDIM;
#pragma unroll
  for (int t = 0; t < 4; ++t)
#pragma unroll
    for (int c = 0; c < 2; ++c)
      b[t][c] = *(const bf16x8*)(wtk + (t * 16 + r) * CDIM + c * 32 + h * 8);

  const int* imk = in_map  + (size_t)k * MPAIRS;
  const int* omk = out_map + (size_t)k * MPAIRS;
  const unsigned short* rpk = rankpack + (size_t)k * MPAIRS;
  const unsigned int pbase = (unsigned int)pass * (unsigned int)PASSC;
  const int ntiles = MPAIRS / 16;
  const int wstride = gridDim.x * 4;

  for (int tile = blockIdx.x * 4 + wave; tile < ntiles; tile += wstride) {
    const int base = tile * 16;
    const int in_row = imk[base + r];
    const short* arow = a_bf16 + (size_t)in_row * CDIM;
    bf16x8 a0 = *(const bf16x8*)(arow + h * 8);
    bf16x8 a1 = *(const bf16x8*)(arow + 32 + h * 8);

    // deterministic CSR slot (issued early; latency hides under MFMA)
    const int orow = omk[base + r];
    const unsigned int rp = rpk[base + r];
    const unsigned int pos =
        base8[((size_t)pass * NROWS + orow) * NCOPY + (rp & 7u)] + (rp >> 3);

    f32x4 acc[4];
#pragma unroll
    for (int t = 0; t < 4; ++t) {
      acc[t] = (f32x4){0.f, 0.f, 0.f, 0.f};
      acc[t] = __builtin_amdgcn_mfma_f32_16x16x32_bf16(b[t][0], a0, acc[t], 0, 0, 0);
      acc[t] = __builtin_amdgcn_mfma_f32_16x16x32_bf16(b[t][1], a1, acc[t], 0, 0, 0);
    }

    short* crow = contrib + (size_t)(pos - pbase) * CDIM;
#pragma unroll
    for (int t = 0; t < 4; ++t) {
      short4 s4;
      s4.x = f2bf(acc[t][0]); s4.y = f2bf(acc[t][1]);
      s4.z = f2bf(acc[t][2]); s4.w = f2bf(acc[t][3]);
      *(short4*)(crow + t * 16 + h * 4) = s4;
    }
  }
}

// ---- reduce pass: one wave per output row; CONTIGUOUS segment of contrib ----
__global__ __launch_bounds__(256, 8)
void reduce_pass(const short* __restrict__ contrib,
                 const unsigned int* __restrict__ offsets,
                 float* __restrict__ out, int pass)
{
  int gw = (blockIdx.x * blockDim.x + threadIdx.x) >> 6;   // global wave = out row
  if (gw >= NROWS) return;
  int lane = threadIdx.x & 63;
  const unsigned int* offp = offsets + (size_t)pass * NROWS;
  const unsigned int pbase = (unsigned int)pass * (unsigned int)PASSC;
  unsigned int s = offp[gw], e = offp[gw + 1];

  float acc = 0.f;
  if (pass > 0) {
    if (s == e) return;                       // nothing to add this pass
    acc = out[(size_t)gw * CDIM + lane];
  }
  const uint16_t* cb = (const uint16_t*)contrib;
  for (unsigned int j = s; j < e; ++j) {
    acc += bf2f(cb[(size_t)(j - pbase) * CDIM + lane]);
  }
  out[(size_t)gw * CDIM + lane] = acc;
}

extern "C" void kernel_launch(void* const* d_in, const int* in_sizes, int n_in,
                              void* d_out, int out_size, void* d_ws, size_t ws_size,
                              hipStream_t stream) {
  const float* in_feats = (const float*)d_in[0];   // [200000][64]
  const float* kernel   = (const float*)d_in[1];   // [27][64][64]
  const int*   in_map   = (const int*)d_in[2];     // [27][150000]
  const int*   out_map  = (const int*)d_in[3];     // [27][150000]
  float* out = (float*)d_out;                      // [200000][64]

  uint8_t* ws = (uint8_t*)d_ws;
  size_t off = 0;
  auto alloc = [&](size_t bytes) -> void* {
    void* p = ws + off;
    off += (bytes + 255) & ~(size_t)255;
    return p;
  };
  short* in_bf16          = (short*)alloc((size_t)NROWS * CDIM * 2);          // 25.6 MB
  short* wt_bf16          = (short*)alloc((size_t)KVOL * CDIM * CDIM * 2);    // 221 KB
  unsigned int* cnt8      = (unsigned int*)alloc((size_t)NCOPY * NBINS * 4);  // 19.2 MB
  unsigned int* offsets   = (unsigned int*)alloc((size_t)(NBINS + 1) * 4);    // 2.4 MB
  unsigned int* bsum      = (unsigned int*)alloc(4096);
  unsigned short* rankpk  = (unsigned short*)alloc((size_t)TOTALC * 2);       // 8.1 MB
  unsigned int* base8     = (unsigned int*)alloc((size_t)NBINS * NCOPY * 4);  // 19.2 MB
  short* contrib          = (short*)alloc((size_t)PASSC * CDIM * 2);          // 172.8 MB

  hipMemsetAsync(cnt8, 0, (size_t)NCOPY * NBINS * 4, stream);

  cvt_feats<<<2048, 256, 0, stream>>>(in_feats, in_bf16, NROWS * CDIM / 8);
  cvt_w<<<KVOL, 256, 0, stream>>>(kernel, wt_bf16);

  const int cb = (TOTALC + 255) / 256;
  count_rank<<<cb, 256, 0, stream>>>(out_map, cnt8, rankpk);

  const int sb = (NBINS + 1023) / 1024;   // 587
  scan_local<<<sb, 1024, 0, stream>>>(cnt8, offsets, bsum);
  scan_bsum<<<1, 1024, 0, stream>>>(bsum, sb);
  scan_apply<<<sb, 1024, 0, stream>>>(offsets, bsum);
  base_fill<<<sb, 1024, 0, stream>>>(cnt8, offsets, base8);

  for (int p = 0; p < NPASS; ++p) {
    dim3 g(192, KPP);
    gemm_pass<<<g, 256, 0, stream>>>(in_bf16, wt_bf16, in_map, out_map,
                                     rankpk, base8, contrib, p);
    reduce_pass<<<NROWS / 4, 256, 0, stream>>>(contrib, offsets, out, p);
  }
}